// Round 4
// baseline (1079.996 us; speedup 1.0000x reference)
//
#include <hip/hip_runtime.h>
#include <hip/hip_fp16.h>
#include <stdint.h>

#define NEG_SLOPE 0.01f
#define EPSF 1e-10f
#define NB_SHIFT 11
#define NB_ROWS (1 << NB_SHIFT)   // 2048 rows per bucket
#define NB_MAX 512                // supports N up to 2^20
#define BP_EPT 16
#define BP_EDGES (256 * BP_EPT)   // 4096 edges per binpairs block
#define CB_CAP 17408              // csrbuild LDS staging (mean 16360, sigma 128; +fallback)
#define DS_NODES 4096             // dsort block span

__device__ __forceinline__ float lrelu(float x){
  return fmaxf(x, 0.f) + NEG_SLOPE * fminf(x, 0.f);
}

__device__ __forceinline__ unsigned pkh2(float a, float b){
  __half2 h = __floats2half2_rn(a, b);
  return __builtin_bit_cast(unsigned, h);
}

__device__ __forceinline__ float2 uph2(unsigned u){
  return __half22float2(__builtin_bit_cast(__half2, u));
}

// K0: repack W [2][64][32] fp32 -> Wf [64 k][64 j] (j = c*32+jj), b -> bf[64]
__global__ void conv_wb(const float* __restrict__ W,
                        const float* __restrict__ b,
                        float* __restrict__ Wf, float* __restrict__ bf){
  int i = blockIdx.x * blockDim.x + threadIdx.x;
  for (int idx = i; idx < 64 * 64; idx += blockDim.x * gridDim.x){
    int k = idx >> 6, j = idx & 63;
    int c = j >> 5, jj = j & 31;
    Wf[idx] = W[c * 2048 + k * 32 + jj];
  }
  if (i < 64) bf[i] = b[i];
}

// K1: projection -> fp16 h2 [n][64]. Full row hoisted to regs first so all
// 16 dwordx4 loads are in flight together (single fetch per line, MSHR-merged).
__global__ __launch_bounds__(256) void proj(const float* __restrict__ ego,
                                            const float* __restrict__ Wf,
                                            const float* __restrict__ bf,
                                            __half* __restrict__ h2, int N){
  int n = blockIdx.x * 256 + threadIdx.x;
  if (n >= N) return;
  const float4* ep = (const float4*)(ego + (size_t)n * 64);
  float4 rowv[16];
  #pragma unroll
  for (int kk = 0; kk < 16; kk++) rowv[kk] = ep[kk];
  float acc[64];
  #pragma unroll
  for (int j = 0; j < 64; j++) acc[j] = bf[j];
  #pragma unroll
  for (int kk = 0; kk < 16; kk++){
    float ev[4] = {rowv[kk].x, rowv[kk].y, rowv[kk].z, rowv[kk].w};
    const float* wbase = Wf + kk * 4 * 64;
    #pragma unroll
    for (int t = 0; t < 4; t++){
      float ek = ev[t];
      const float* wrow = wbase + t * 64;
      #pragma unroll
      for (int j = 0; j < 64; j++) acc[j] = fmaf(ek, wrow[j], acc[j]);
    }
  }
  uint4* dst = (uint4*)(h2 + (size_t)n * 64);
  #pragma unroll
  for (int v = 0; v < 8; v++){
    uint4 o;
    o.x = pkh2(lrelu(acc[8 * v + 0]), lrelu(acc[8 * v + 1]));
    o.y = pkh2(lrelu(acc[8 * v + 2]), lrelu(acc[8 * v + 3]));
    o.z = pkh2(lrelu(acc[8 * v + 4]), lrelu(acc[8 * v + 5]));
    o.w = pkh2(lrelu(acc[8 * v + 6]), lrelu(acc[8 * v + 7]));
    dst[v] = o;
  }
}

// K2: bucket histogram (LDS-staged). bucket = row >> NB_SHIFT
__global__ __launch_bounds__(256) void bhist(const int* __restrict__ row,
                                             int* __restrict__ bcnt, int E, int nb){
  __shared__ int lh[NB_MAX];
  for (int i = threadIdx.x; i < nb; i += 256) lh[i] = 0;
  __syncthreads();
  int i = blockIdx.x * 256 + threadIdx.x;
  int stride = gridDim.x * 256;
  for (; i < E; i += stride) atomicAdd(&lh[row[i] >> NB_SHIFT], 1);
  __syncthreads();
  for (int j = threadIdx.x; j < nb; j += 256){
    int v = lh[j];
    if (v) atomicAdd(&bcnt[j], v);
  }
}

// K3: exclusive scan of bucket counts, init bucket cursors
__global__ __launch_bounds__(512) void bscan(const int* __restrict__ bcnt,
                                             int* __restrict__ bbase,
                                             int* __restrict__ bcur, int nb){
  __shared__ int sh[NB_MAX];
  int t = threadIdx.x;
  int v = (t < nb) ? bcnt[t] : 0;
  sh[t] = v; __syncthreads();
  for (int off = 1; off < NB_MAX; off <<= 1){
    int a = (t >= off) ? sh[t - off] : 0;
    __syncthreads();
    sh[t] += a;
    __syncthreads();
  }
  if (t < nb){
    int e = sh[t] - v;
    bbase[t] = e;
    bcur[t] = e;
  }
}

// K4: bin edges into bucket-contiguous tmp, LDS-sorted so global writes
// are coalesced within per-(block,bucket) runs. packed = (rowLow11<<20)|col
__global__ __launch_bounds__(256) void binpairs(const int* __restrict__ row,
                                                const int* __restrict__ col,
                                                int* __restrict__ bcur,
                                                unsigned int* __restrict__ tmp,
                                                int E, int nb){
  __shared__ int lh[NB_MAX];
  __shared__ int lofs[NB_MAX];
  __shared__ int lbase[NB_MAX];
  __shared__ int wsum[256];
  __shared__ unsigned int sval[BP_EDGES];
  __shared__ unsigned int sdst[BP_EDGES];
  int t = threadIdx.x;
  for (int i = t; i < nb; i += 256) lh[i] = 0;
  __syncthreads();
  int e0 = blockIdx.x * BP_EDGES;
  int tot = E - e0; if (tot > BP_EDGES) tot = BP_EDGES;
  int r[BP_EPT], c[BP_EPT], mo[BP_EPT];
  #pragma unroll
  for (int k = 0; k < BP_EPT; k++){
    int e = e0 + k * 256 + t;
    if (e < E){
      r[k] = row[e];
      c[k] = col[e];
      mo[k] = atomicAdd(&lh[r[k] >> NB_SHIFT], 1);
    } else r[k] = -1;
  }
  __syncthreads();
  int c0 = (2 * t < nb) ? lh[2 * t] : 0;
  int c1 = (2 * t + 1 < nb) ? lh[2 * t + 1] : 0;
  int s = c0 + c1;
  wsum[t] = s; __syncthreads();
  for (int off = 1; off < 256; off <<= 1){
    int a = (t >= off) ? wsum[t - off] : 0;
    __syncthreads();
    wsum[t] += a;
    __syncthreads();
  }
  int tb = wsum[t] - s;
  if (2 * t < nb){
    lofs[2 * t] = tb;
    if (c0) lbase[2 * t] = atomicAdd(&bcur[2 * t], c0);
  }
  if (2 * t + 1 < nb){
    lofs[2 * t + 1] = tb + c0;
    if (c1) lbase[2 * t + 1] = atomicAdd(&bcur[2 * t + 1], c1);
  }
  __syncthreads();
  #pragma unroll
  for (int k = 0; k < BP_EPT; k++){
    if (r[k] >= 0){
      int b = r[k] >> NB_SHIFT;
      int slot = lofs[b] + mo[k];
      sval[slot] = ((unsigned int)(r[k] & (NB_ROWS - 1)) << 20) | (unsigned int)c[k];
      sdst[slot] = (unsigned int)(lbase[b] + mo[k]);
    }
  }
  __syncthreads();
  for (int i = t; i < tot; i += 256) tmp[sdst[i]] = sval[i];
}

// K5: per-bucket CSR finalize -> odeg (offs,deg packed) + colp.
// CB_CAP sized for 2 blocks/CU (78 KB LDS).
__global__ __launch_bounds__(512) void csrbuild(const unsigned int* __restrict__ tmp,
                                                const int* __restrict__ bbase,
                                                const int* __restrict__ bcnt,
                                                int2* __restrict__ odeg,
                                                int* __restrict__ colp,
                                                int N){
  __shared__ int cnt[NB_ROWS];
  __shared__ int wsum[512];
  __shared__ int scol[CB_CAP];
  int b = blockIdx.x;
  int r0 = b << NB_SHIFT;
  int t = threadIdx.x;
  for (int i = t; i < NB_ROWS; i += 512) cnt[i] = 0;
  __syncthreads();
  int s = bbase[b];
  int cb = bcnt[b];
  int e = s + cb;
  for (int p = s + t; p < e; p += 512) atomicAdd(&cnt[tmp[p] >> 20], 1);
  __syncthreads();
  int base_i = t * 4;
  int dv[4], loc[4];
  int sum = 0;
  #pragma unroll
  for (int k = 0; k < 4; k++){
    dv[k] = cnt[base_i + k];
    loc[k] = sum;
    sum += dv[k];
  }
  wsum[t] = sum; __syncthreads();
  for (int off = 1; off < 512; off <<= 1){
    int a = (t >= off) ? wsum[t - off] : 0;
    __syncthreads();
    wsum[t] += a;
    __syncthreads();
  }
  int tbase = wsum[t] - sum;
  #pragma unroll
  for (int k = 0; k < 4; k++){
    int i = base_i + k;
    int o = tbase + loc[k];
    if (r0 + i < N) odeg[r0 + i] = make_int2(s + o, dv[k]);
    cnt[i] = o;
  }
  __syncthreads();
  if (cb <= CB_CAP){
    for (int p = s + t; p < e; p += 512){
      unsigned int v = tmp[p];
      int pos = atomicAdd(&cnt[v >> 20], 1);
      scol[pos] = (int)(v & 0xFFFFFu);
    }
    __syncthreads();
    for (int i = t; i < cb; i += 512) colp[s + i] = scol[i];
  } else {
    for (int p = s + t; p < e; p += 512){
      unsigned int v = tmp[p];
      int pos = atomicAdd(&cnt[v >> 20], 1);
      colp[s + pos] = (int)(v & 0xFFFFFu);
    }
  }
}

// K5.5: block-local counting sort of nodes by degree -> perm.
// Each block sorts a 4096-node span, so |perm[i]-i| < 4096: agg2 waves get
// equal-degree nodes (no lane imbalance) while odeg/colp reads stay local.
__global__ __launch_bounds__(256) void dsort(const int2* __restrict__ odeg,
                                             int* __restrict__ perm, int N){
  __shared__ int hist[256];
  __shared__ int wsum[256];
  __shared__ int sperm[DS_NODES];
  int t = threadIdx.x;
  int base = blockIdx.x * DS_NODES;
  int cnt = N - base; if (cnt > DS_NODES) cnt = DS_NODES;
  hist[t] = 0;
  __syncthreads();
  int rk[16], bn[16];
  #pragma unroll
  for (int k = 0; k < 16; k++){
    int i = k * 256 + t;
    if (i < cnt){
      int d = odeg[base + i].y;
      bn[k] = d > 255 ? 255 : d;
      rk[k] = atomicAdd(&hist[bn[k]], 1);
    } else bn[k] = -1;
  }
  __syncthreads();
  int h = hist[t];
  wsum[t] = h; __syncthreads();
  for (int off = 1; off < 256; off <<= 1){
    int a = (t >= off) ? wsum[t - off] : 0;
    __syncthreads();
    wsum[t] += a;
    __syncthreads();
  }
  __syncthreads();
  hist[t] = wsum[t] - h;   // exclusive bin base (ranks already captured)
  __syncthreads();
  #pragma unroll
  for (int k = 0; k < 16; k++){
    if (bn[k] >= 0){
      int i = k * 256 + t;
      sperm[hist[bn[k]] + rk[k]] = base + i;
    }
  }
  __syncthreads();
  for (int i = t; i < cnt; i += 256) perm[base + i] = sperm[i];
}

// K6: fused dual-channel attention aggregation from fp16 h2, degree-sorted order.
__global__ __launch_bounds__(256) void agg2(const __half* __restrict__ h2,
                                            const int2* __restrict__ odeg,
                                            const int* __restrict__ colp,
                                            const int* __restrict__ perm,
                                            float* __restrict__ out, int N){
  int i0 = blockIdx.x * 256 + threadIdx.x;
  if (i0 >= N) return;
  int n = perm[i0];
  unsigned hrp[32];
  const uint4* hr4 = (const uint4*)(h2 + (size_t)n * 64);
  #pragma unroll
  for (int v = 0; v < 8; v++){
    uint4 q = hr4[v];
    hrp[4 * v + 0] = q.x; hrp[4 * v + 1] = q.y;
    hrp[4 * v + 2] = q.z; hrp[4 * v + 3] = q.w;
  }
  float acc[64];
  #pragma unroll
  for (int j = 0; j < 64; j++) acc[j] = 0.f;
  float l0 = 0.f, l1 = 0.f;
  int2 od = odeg[n];
  int s = od.x, d = od.y;
  for (int p = s; p < s + d; ++p){
    int c = colp[p];
    unsigned hcp[32];
    const uint4* hc4 = (const uint4*)(h2 + (size_t)c * 64);
    #pragma unroll
    for (int v = 0; v < 8; v++){
      uint4 q = hc4[v];
      hcp[4 * v + 0] = q.x; hcp[4 * v + 1] = q.y;
      hcp[4 * v + 2] = q.z; hcp[4 * v + 3] = q.w;
    }
    float dot0 = 0.f, dot1 = 0.f;
    #pragma unroll
    for (int i = 0; i < 16; i++){
      float2 a = uph2(hrp[i]);
      float2 b = uph2(hcp[i]);
      dot0 = fmaf(a.x, b.x, dot0);
      dot0 = fmaf(a.y, b.y, dot0);
    }
    #pragma unroll
    for (int i = 16; i < 32; i++){
      float2 a = uph2(hrp[i]);
      float2 b = uph2(hcp[i]);
      dot1 = fmaf(a.x, b.x, dot1);
      dot1 = fmaf(a.y, b.y, dot1);
    }
    float w0 = __expf(fminf(lrelu(dot0), 80.f));
    float w1 = __expf(fminf(lrelu(dot1), 80.f));
    l0 += w0; l1 += w1;
    #pragma unroll
    for (int i = 0; i < 16; i++){
      float2 b = uph2(hcp[i]);
      acc[2 * i + 0] = fmaf(w0, b.x, acc[2 * i + 0]);
      acc[2 * i + 1] = fmaf(w0, b.y, acc[2 * i + 1]);
    }
    #pragma unroll
    for (int i = 16; i < 32; i++){
      float2 b = uph2(hcp[i]);
      acc[2 * i + 0] = fmaf(w1, b.x, acc[2 * i + 0]);
      acc[2 * i + 1] = fmaf(w1, b.y, acc[2 * i + 1]);
    }
  }
  float inv0 = 1.f / (l0 + EPSF);
  float inv1 = 1.f / (l1 + EPSF);
  float4* op = (float4*)(out + (size_t)n * 64);
  #pragma unroll
  for (int v = 0; v < 16; v++){
    float sc = (v < 8) ? inv0 : inv1;
    float4 o;
    o.x = acc[4 * v + 0] * sc;
    o.y = acc[4 * v + 1] * sc;
    o.z = acc[4 * v + 2] * sc;
    o.w = acc[4 * v + 3] * sc;
    op[v] = o;
  }
}

extern "C" void kernel_launch(void* const* d_in, const int* in_sizes, int n_in,
                              void* d_out, int out_size, void* d_ws, size_t ws_size,
                              hipStream_t stream){
  const float* ego = (const float*)d_in[0];
  const float* W   = (const float*)d_in[1];
  const float* b   = (const float*)d_in[2];
  const int* row = (const int*)d_in[3];
  const int* col = (const int*)d_in[4];
  int N = in_sizes[0] / 64;
  int E = in_sizes[3];
  float* out = (float*)d_out;

  char* ws = (char*)d_ws;
  float* Wf = (float*)ws;                       // 4096 f
  float* bf = Wf + 4096;                        // 64 f
  size_t off = 32768;
  __half* h2 = (__half*)(ws + off); off += (size_t)N * 64 * 2;
  int2* odeg = (int2*)(ws + off); off += (size_t)N * 8;
  int* perm  = (int*)(ws + off); off += (size_t)N * 4;
  int* bcnt  = (int*)(ws + off); off += NB_MAX * 4;
  int* bbase = (int*)(ws + off); off += NB_MAX * 4;
  int* bcur  = (int*)(ws + off); off += NB_MAX * 4;
  unsigned int* tmp = (unsigned int*)(ws + off); off += (size_t)E * 4;
  int* colp = (int*)(ws + off);

  int nb = (N + NB_ROWS - 1) >> NB_SHIFT;       // 489 for N=1e6

  hipMemsetAsync(bcnt, 0, NB_MAX * 4, stream);
  conv_wb<<<16, 256, 0, stream>>>(W, b, Wf, bf);
  proj<<<(N + 255) / 256, 256, 0, stream>>>(ego, Wf, bf, h2, N);
  bhist<<<1024, 256, 0, stream>>>(row, bcnt, E, nb);
  bscan<<<1, NB_MAX, 0, stream>>>(bcnt, bbase, bcur, nb);
  binpairs<<<(E + BP_EDGES - 1) / BP_EDGES, 256, 0, stream>>>(row, col, bcur, tmp, E, nb);
  csrbuild<<<nb, 512, 0, stream>>>(tmp, bbase, bcnt, odeg, colp, N);
  dsort<<<(N + DS_NODES - 1) / DS_NODES, 256, 0, stream>>>(odeg, perm, N);
  agg2<<<(N + 255) / 256, 256, 0, stream>>>(h2, odeg, colp, perm, out, N);
}